// Round 1
// baseline (479.656 us; speedup 1.0000x reference)
//
#include <hip/hip_runtime.h>

// BlocksparseFixedSelfAttention: B=4, T=2048, EMB=512, KBLK=64, fp32.
// Pipeline: [gemm K][gemm Q][gemm V] -> [h1 block-diag causal][h2 column-summary] -> [gemm out]
// ws layout (floats): Kt[8192*512] Qt[8192*512] Vt[8192*512] comb[8192*1024]  = 80 MiB

constexpr int TDIM  = 2048;
constexpr int EMB_D = 512;
constexpr int BB    = 4;
constexpr int NBLK  = 32;   // T / 64

// ---------------------------------------------------------------------------
// Generic TN GEMM: C[m][n] = sum_k A[m][k] * W[n][k] + bias[n]
// 64x64 tile, BK=16, 256 threads, 4x4 microtile.
// ---------------------------------------------------------------------------
__global__ __launch_bounds__(256) void gemm_tn_k(
    const float* __restrict__ A, int lda,
    const float* __restrict__ W, int ldw,
    const float* __restrict__ bias,
    float* __restrict__ C, int ldc, int K)
{
    __shared__ float As[16][64];
    __shared__ float Ws[16][64];
    const int bm = blockIdx.x * 64;
    const int bn = blockIdx.y * 64;
    const int tid = threadIdx.x;
    const int tx = tid & 15, ty = tid >> 4;
    const int lm = tid >> 2;           // 0..63 tile row
    const int lk = (tid & 3) << 2;     // 0,4,8,12
    float acc[4][4] = {};
    const float* Ap = A + (size_t)(bm + lm) * lda + lk;
    const float* Wp = W + (size_t)(bn + lm) * ldw + lk;
    for (int k0 = 0; k0 < K; k0 += 16) {
        float4 av = *(const float4*)(Ap + k0);
        float4 wv = *(const float4*)(Wp + k0);
        __syncthreads();
        As[lk+0][lm]=av.x; As[lk+1][lm]=av.y; As[lk+2][lm]=av.z; As[lk+3][lm]=av.w;
        Ws[lk+0][lm]=wv.x; Ws[lk+1][lm]=wv.y; Ws[lk+2][lm]=wv.z; Ws[lk+3][lm]=wv.w;
        __syncthreads();
        #pragma unroll
        for (int kk = 0; kk < 16; ++kk) {
            float4 a = *(const float4*)(&As[kk][ty<<2]);
            float4 b = *(const float4*)(&Ws[kk][tx<<2]);
            float ar[4] = {a.x,a.y,a.z,a.w};
            float br[4] = {b.x,b.y,b.z,b.w};
            #pragma unroll
            for (int i=0;i<4;i++)
                #pragma unroll
                for (int j=0;j<4;j++)
                    acc[i][j] += ar[i]*br[j];
        }
    }
    #pragma unroll
    for (int i=0;i<4;i++) {
        const int m = bm + (ty<<2) + i;
        const int n = bn + (tx<<2);
        float4 o;
        o.x = acc[i][0] + bias[n+0];
        o.y = acc[i][1] + bias[n+1];
        o.z = acc[i][2] + bias[n+2];
        o.w = acc[i][3] + bias[n+3];
        *(float4*)(C + (size_t)m*ldc + n) = o;
    }
}

// ---------------------------------------------------------------------------
// h1: per (block, batch): S[r][c] = K_row(r) . Q_row(c) over EMB, mask c<=r
//     (within 64-block), then h1 = S @ V_blk.  Writes comb[:, 0:512].
// ---------------------------------------------------------------------------
__global__ __launch_bounds__(256) void h1_k(
    const float* __restrict__ Kt, const float* __restrict__ Qt,
    const float* __restrict__ Vt, float* __restrict__ comb)
{
    const int blk = blockIdx.x;
    const int b   = blockIdx.y;
    const size_t row0 = (size_t)b * TDIM + (size_t)blk * 64;
    const int tid = threadIdx.x;
    const int tx = tid & 15, ty = tid >> 4;
    const int lm = tid >> 2;
    const int lk = (tid & 3) << 2;
    __shared__ float Ks[16][64];
    __shared__ float Qs[16][64];
    __shared__ float Sh[64][65];
    __shared__ float Vs[64][68];
    float acc[4][4] = {};
    const float* Kp = Kt + (row0 + lm) * EMB_D + lk;
    const float* Qp = Qt + (row0 + lm) * EMB_D + lk;
    for (int k0 = 0; k0 < EMB_D; k0 += 16) {
        float4 kv = *(const float4*)(Kp + k0);
        float4 qv = *(const float4*)(Qp + k0);
        __syncthreads();
        Ks[lk+0][lm]=kv.x; Ks[lk+1][lm]=kv.y; Ks[lk+2][lm]=kv.z; Ks[lk+3][lm]=kv.w;
        Qs[lk+0][lm]=qv.x; Qs[lk+1][lm]=qv.y; Qs[lk+2][lm]=qv.z; Qs[lk+3][lm]=qv.w;
        __syncthreads();
        #pragma unroll
        for (int kk = 0; kk < 16; ++kk) {
            float4 a = *(const float4*)(&Ks[kk][ty<<2]);
            float4 q = *(const float4*)(&Qs[kk][tx<<2]);
            float ar[4] = {a.x,a.y,a.z,a.w};
            float qr[4] = {q.x,q.y,q.z,q.w};
            #pragma unroll
            for (int i=0;i<4;i++)
                #pragma unroll
                for (int j=0;j<4;j++)
                    acc[i][j] += ar[i]*qr[j];
        }
    }
    // mask (col <= row) and stash S in LDS
    #pragma unroll
    for (int i=0;i<4;i++) {
        const int r = (ty<<2) + i;
        #pragma unroll
        for (int j=0;j<4;j++) {
            const int c = (tx<<2) + j;
            Sh[r][c] = (c <= r) ? acc[i][j] : 0.0f;
        }
    }
    // h1 = S @ V_blk, e-chunks of 64
    for (int e0 = 0; e0 < EMB_D; e0 += 64) {
        __syncthreads();   // prior compute done (and Sh visible on first iter)
        #pragma unroll
        for (int it=0; it<4; ++it) {
            const int c = (it<<4) + (tid>>4);
            const int e = (tid&15)<<2;
            float4 v = *(const float4*)(Vt + (row0 + c)*EMB_D + e0 + e);
            *(float4*)(&Vs[c][e]) = v;
        }
        __syncthreads();
        float a2[4][4] = {};
        const int cend = (ty<<2) + 4;  // rows 4ty..4ty+3 only need c <= 4ty+3; S==0 beyond row
        for (int c = 0; c < cend; ++c) {
            float4 v = *(const float4*)(&Vs[c][tx<<2]);
            const float s0 = Sh[(ty<<2)+0][c];
            const float s1 = Sh[(ty<<2)+1][c];
            const float s2 = Sh[(ty<<2)+2][c];
            const float s3 = Sh[(ty<<2)+3][c];
            a2[0][0]+=s0*v.x; a2[0][1]+=s0*v.y; a2[0][2]+=s0*v.z; a2[0][3]+=s0*v.w;
            a2[1][0]+=s1*v.x; a2[1][1]+=s1*v.y; a2[1][2]+=s1*v.z; a2[1][3]+=s1*v.w;
            a2[2][0]+=s2*v.x; a2[2][1]+=s2*v.y; a2[2][2]+=s2*v.z; a2[2][3]+=s2*v.w;
            a2[3][0]+=s3*v.x; a2[3][1]+=s3*v.y; a2[3][2]+=s3*v.z; a2[3][3]+=s3*v.w;
        }
        #pragma unroll
        for (int i=0;i<4;i++) {
            float4 o = {a2[i][0], a2[i][1], a2[i][2], a2[i][3]};
            *(float4*)(comb + (row0 + (ty<<2) + i) * (2*EMB_D) + e0 + (tx<<2)) = o;
        }
    }
}

// ---------------------------------------------------------------------------
// h2: per (row-tile R, batch): S2[r][m] = K_row(64R+r) . Q_row(64m) over EMB,
//     valid m <= R (tile-uniform mask!), then h2 = S2 @ Vsel where
//     Vsel[m] = V_row(64m).  Writes comb[:, 512:1024].
// ---------------------------------------------------------------------------
__global__ __launch_bounds__(256) void h2_k(
    const float* __restrict__ Kt, const float* __restrict__ Qt,
    const float* __restrict__ Vt, float* __restrict__ comb)
{
    const int R = blockIdx.x;       // row tile 0..31
    const int b = blockIdx.y;
    const size_t row0 = (size_t)b * TDIM + (size_t)R * 64;
    const size_t brow = (size_t)b * TDIM;
    const int tid = threadIdx.x;
    __shared__ float Ks[16][64];
    __shared__ float Qs2[16][32];
    __shared__ float Sh2[64][33];
    __shared__ float Vs2[32][68];
    // S2 phase: 64x32 out, 2x4 microtile
    const int sty = tid >> 3;       // 0..31 -> rows 2*sty+i
    const int stx = tid & 7;        // cols 4*stx+j
    const int lm = tid >> 2, lk = (tid & 3) << 2;
    float acc[2][4] = {};
    const float* Kp = Kt + (row0 + lm)*EMB_D + lk;
    for (int k0 = 0; k0 < EMB_D; k0 += 16) {
        float4 kv = *(const float4*)(Kp + k0);
        float4 qv = {0,0,0,0};
        if (tid < 128)  // 32 rows x 16 k = 512 floats
            qv = *(const float4*)(Qt + (brow + (size_t)lm*64)*EMB_D + k0 + lk);
        __syncthreads();
        Ks[lk+0][lm]=kv.x; Ks[lk+1][lm]=kv.y; Ks[lk+2][lm]=kv.z; Ks[lk+3][lm]=kv.w;
        if (tid < 128) {
            Qs2[lk+0][lm]=qv.x; Qs2[lk+1][lm]=qv.y; Qs2[lk+2][lm]=qv.z; Qs2[lk+3][lm]=qv.w;
        }
        __syncthreads();
        #pragma unroll
        for (int kk = 0; kk < 16; ++kk) {
            const float a0 = Ks[kk][(sty<<1)+0];
            const float a1 = Ks[kk][(sty<<1)+1];
            float4 q = *(const float4*)(&Qs2[kk][stx<<2]);
            acc[0][0]+=a0*q.x; acc[0][1]+=a0*q.y; acc[0][2]+=a0*q.z; acc[0][3]+=a0*q.w;
            acc[1][0]+=a1*q.x; acc[1][1]+=a1*q.y; acc[1][2]+=a1*q.z; acc[1][3]+=a1*q.w;
        }
    }
    #pragma unroll
    for (int i=0;i<2;i++)
        #pragma unroll
        for (int j=0;j<4;j++) {
            const int m = (stx<<2)+j;
            Sh2[(sty<<1)+i][m] = (m <= R) ? acc[i][j] : 0.0f;
        }
    // h2 = S2 @ Vsel, e-chunks of 64; 4x4 microtile
    const int tx = tid & 15, ty = tid >> 4;
    const int mend = R + 1;
    for (int e0 = 0; e0 < EMB_D; e0 += 64) {
        __syncthreads();
        #pragma unroll
        for (int it=0; it<2; ++it) {
            const int m = (it<<4) + (tid>>4);
            const int e = (tid&15)<<2;
            float4 v = *(const float4*)(Vt + (brow + (size_t)m*64)*EMB_D + e0 + e);
            *(float4*)(&Vs2[m][e]) = v;
        }
        __syncthreads();
        float a2[4][4] = {};
        for (int m = 0; m < mend; ++m) {
            float4 v = *(const float4*)(&Vs2[m][tx<<2]);
            const float s0 = Sh2[(ty<<2)+0][m];
            const float s1 = Sh2[(ty<<2)+1][m];
            const float s2 = Sh2[(ty<<2)+2][m];
            const float s3 = Sh2[(ty<<2)+3][m];
            a2[0][0]+=s0*v.x; a2[0][1]+=s0*v.y; a2[0][2]+=s0*v.z; a2[0][3]+=s0*v.w;
            a2[1][0]+=s1*v.x; a2[1][1]+=s1*v.y; a2[1][2]+=s1*v.z; a2[1][3]+=s1*v.w;
            a2[2][0]+=s2*v.x; a2[2][1]+=s2*v.y; a2[2][2]+=s2*v.z; a2[2][3]+=s2*v.w;
            a2[3][0]+=s3*v.x; a2[3][1]+=s3*v.y; a2[3][2]+=s3*v.z; a2[3][3]+=s3*v.w;
        }
        #pragma unroll
        for (int i=0;i<4;i++) {
            float4 o = {a2[i][0], a2[i][1], a2[i][2], a2[i][3]};
            *(float4*)(comb + (row0 + (ty<<2) + i) * (2*EMB_D) + 512 + e0 + (tx<<2)) = o;
        }
    }
}

extern "C" void kernel_launch(void* const* d_in, const int* in_sizes, int n_in,
                              void* d_out, int out_size, void* d_ws, size_t ws_size,
                              hipStream_t stream)
{
    const float* x  = (const float*)d_in[0];
    const float* Wk = (const float*)d_in[1];
    const float* bk = (const float*)d_in[2];
    const float* Wq = (const float*)d_in[3];
    const float* bq = (const float*)d_in[4];
    const float* Wv = (const float*)d_in[5];
    const float* bv = (const float*)d_in[6];
    const float* Wu = (const float*)d_in[7];
    const float* bu = (const float*)d_in[8];
    // d_in[9]/d_in[10] = coords1/coords2: structure decoded analytically, unused.
    float* out = (float*)d_out;

    const size_t NTOK = (size_t)BB * TDIM;   // 8192
    float* Kt   = (float*)d_ws;
    float* Qt   = Kt + NTOK * EMB_D;
    float* Vt   = Qt + NTOK * EMB_D;
    float* comb = Vt + NTOK * EMB_D;         // NTOK x 1024

    dim3 blk(256);
    dim3 g1(NTOK/64, EMB_D/64);              // 128 x 8
    hipLaunchKernelGGL(gemm_tn_k, g1, blk, 0, stream, x, EMB_D, Wk, EMB_D, bk, Kt, EMB_D, EMB_D);
    hipLaunchKernelGGL(gemm_tn_k, g1, blk, 0, stream, x, EMB_D, Wq, EMB_D, bq, Qt, EMB_D, EMB_D);
    hipLaunchKernelGGL(gemm_tn_k, g1, blk, 0, stream, x, EMB_D, Wv, EMB_D, bv, Vt, EMB_D, EMB_D);
    dim3 g2(NBLK, BB);                       // 32 x 4
    hipLaunchKernelGGL(h1_k, g2, blk, 0, stream, Kt, Qt, Vt, comb);
    hipLaunchKernelGGL(h2_k, g2, blk, 0, stream, Kt, Qt, Vt, comb);
    hipLaunchKernelGGL(gemm_tn_k, g1, blk, 0, stream, comb, 2*EMB_D, Wu, 2*EMB_D, bu, out, EMB_D, 2*EMB_D);
}

// Round 2
// 188.281 us; speedup vs baseline: 2.5476x; 2.5476x over previous
//
#include <hip/hip_runtime.h>

// BlocksparseFixedSelfAttention: B=4, T=2048, EMB=512, KBLK=64.
// R2: bf16-MFMA GEMMs (m97 structure), fp32 sparse heads fused into one launch.
// ws (bytes): Kt f32 16M @0 | Qt 16M @16M | Vt 16M @32M | comb bf16 16M @48M |
//             xb bf16 8M @64M | wkb @72M | wqb @73M | wvb @74M | wub @75M  (76 MiB total)

typedef unsigned short u16;
typedef __attribute__((ext_vector_type(8))) short short8;
typedef __attribute__((ext_vector_type(4))) float f32x4;

constexpr int TDIM  = 2048;
constexpr int EMB_D = 512;
constexpr int BB    = 4;
constexpr int NBLK  = 32;   // T / 64

__device__ __forceinline__ u16 f2b(float f) {
    unsigned u = __float_as_uint(f);
    unsigned r = (u + 0x7FFFu + ((u >> 16) & 1u)) >> 16;
    return (u16)r;
}

// ---------------------------------------------------------------------------
// bf16 MFMA GEMM core: C[m][n] = sum_k A[m][k]*W[n][k] + bias[n], fp32 out.
// 128x128 tile, BK=32, 256 threads (4 waves), wave = 64x64 via 4x4 MFMAs.
// A,W row-major bf16, K-contiguous. global_load_lds width-16 staging.
// ---------------------------------------------------------------------------
__device__ __forceinline__ void gemm_bf16_core(
    const u16* __restrict__ A, int lda,
    const u16* __restrict__ W, int ldw,
    const float* __restrict__ bias,
    float* __restrict__ C, int ldc, int K,
    int bm, int bn)
{
    __shared__ u16 As[128 * 32];
    __shared__ u16 Bs[128 * 32];
    const int tid  = threadIdx.x;
    const int wid  = tid >> 6;
    const int lane = tid & 63;
    const int l15  = lane & 15;
    const int quad = lane >> 4;
    const int wm = (wid & 1) * 64;
    const int wn = (wid >> 1) * 64;

    f32x4 acc[4][4] = {};

    // staging map: thread t covers LDS bytes t*16 => row t>>2, k-chunk (t&3)*8
    const int srow  = tid >> 2;          // 0..63
    const int skoff = (tid & 3) * 8;
    const u16* Ag = A + (size_t)(bm + srow) * lda + skoff;
    const u16* Wg = W + (size_t)(bn + srow) * ldw + skoff;
    char* AsBase = (char*)As + wid * 1024;   // wave-uniform LDS base
    char* BsBase = (char*)Bs + wid * 1024;

    for (int k0 = 0; k0 < K; k0 += 32) {
        __syncthreads();
        __builtin_amdgcn_global_load_lds(
            (const __attribute__((address_space(1))) void*)(Ag + k0),
            (__attribute__((address_space(3))) void*)AsBase, 16, 0, 0);
        __builtin_amdgcn_global_load_lds(
            (const __attribute__((address_space(1))) void*)(Ag + (size_t)64 * lda + k0),
            (__attribute__((address_space(3))) void*)(AsBase + 4096), 16, 0, 0);
        __builtin_amdgcn_global_load_lds(
            (const __attribute__((address_space(1))) void*)(Wg + k0),
            (__attribute__((address_space(3))) void*)BsBase, 16, 0, 0);
        __builtin_amdgcn_global_load_lds(
            (const __attribute__((address_space(1))) void*)(Wg + (size_t)64 * ldw + k0),
            (__attribute__((address_space(3))) void*)(BsBase + 4096), 16, 0, 0);
        __syncthreads();   // compiler emits s_waitcnt vmcnt(0) before barrier -> LDS ready

        short8 a[4], b[4];
        #pragma unroll
        for (int i = 0; i < 4; ++i)
            a[i] = *(const short8*)((const short*)As + (wm + 16 * i + l15) * 32 + quad * 8);
        #pragma unroll
        for (int j = 0; j < 4; ++j)
            b[j] = *(const short8*)((const short*)Bs + (wn + 16 * j + l15) * 32 + quad * 8);
        #pragma unroll
        for (int i = 0; i < 4; ++i)
            #pragma unroll
            for (int j = 0; j < 4; ++j)
                acc[i][j] = __builtin_amdgcn_mfma_f32_16x16x32_bf16(a[i], b[j], acc[i][j], 0, 0, 0);
    }

    // epilogue: C/D layout col=lane&15, row=quad*4+reg
    #pragma unroll
    for (int i = 0; i < 4; ++i) {
        #pragma unroll
        for (int j = 0; j < 4; ++j) {
            const int col = bn + wn + 16 * j + l15;
            const float bv = bias[col];
            #pragma unroll
            for (int r = 0; r < 4; ++r) {
                const int row = bm + wm + 16 * i + quad * 4 + r;
                C[(size_t)row * ldc + col] = acc[i][j][r] + bv;
            }
        }
    }
}

__global__ __launch_bounds__(256) void qkv_gemm_k(
    const u16* __restrict__ xb,
    const u16* __restrict__ wkb, const u16* __restrict__ wqb, const u16* __restrict__ wvb,
    const float* __restrict__ bk, const float* __restrict__ bq, const float* __restrict__ bv,
    float* __restrict__ Kt, float* __restrict__ Qt, float* __restrict__ Vt)
{
    const u16* W; const float* bias; float* C;
    if (blockIdx.z == 0)      { W = wkb; bias = bk; C = Kt; }
    else if (blockIdx.z == 1) { W = wqb; bias = bq; C = Qt; }
    else                      { W = wvb; bias = bv; C = Vt; }
    gemm_bf16_core(xb, EMB_D, W, EMB_D, bias, C, EMB_D, EMB_D,
                   blockIdx.x * 128, blockIdx.y * 128);
}

__global__ __launch_bounds__(256) void out_gemm_k(
    const u16* __restrict__ combb, const u16* __restrict__ wub,
    const float* __restrict__ bu, float* __restrict__ out)
{
    gemm_bf16_core(combb, 2 * EMB_D, wub, 2 * EMB_D, bu, out, EMB_D, 2 * EMB_D,
                   blockIdx.x * 128, blockIdx.y * 128);
}

// ---------------------------------------------------------------------------
// cast: x + 4 weights -> bf16. blockIdx.y selects array. 4 elems/thread.
// ---------------------------------------------------------------------------
__global__ __launch_bounds__(256) void cast_k(
    const float* __restrict__ x, const float* __restrict__ wk, const float* __restrict__ wq,
    const float* __restrict__ wv, const float* __restrict__ wu,
    u16* __restrict__ xb, u16* __restrict__ wkb, u16* __restrict__ wqb,
    u16* __restrict__ wvb, u16* __restrict__ wub)
{
    const int s = blockIdx.y;
    int n; const float* src; u16* dst;
    switch (s) {
        case 0: n = 4194304; src = x;  dst = xb;  break;
        case 1: n = 262144;  src = wk; dst = wkb; break;
        case 2: n = 262144;  src = wq; dst = wqb; break;
        case 3: n = 262144;  src = wv; dst = wvb; break;
        default: n = 524288; src = wu; dst = wub; break;
    }
    const int idx = (blockIdx.x * 256 + threadIdx.x) * 4;
    if (idx >= n) return;
    float4 v = *(const float4*)(src + idx);
    ushort4 o = { f2b(v.x), f2b(v.y), f2b(v.z), f2b(v.w) };
    *(ushort4*)(dst + idx) = o;
}

// ---------------------------------------------------------------------------
// h1 (fp32): per (block, batch): S[r][c] = K_r . Q_c, mask c<=r, h1 = S @ V_blk.
// Writes comb[:, 0:512] as bf16.
// ---------------------------------------------------------------------------
__device__ __forceinline__ void h1_body(
    const float* __restrict__ Kt, const float* __restrict__ Qt,
    const float* __restrict__ Vt, u16* __restrict__ comb)
{
    const int blk = blockIdx.x;
    const int b   = blockIdx.y;
    const size_t row0 = (size_t)b * TDIM + (size_t)blk * 64;
    const int tid = threadIdx.x;
    const int tx = tid & 15, ty = tid >> 4;
    const int lm = tid >> 2;
    const int lk = (tid & 3) << 2;
    __shared__ float Ks[16][64];
    __shared__ float Qs[16][64];
    __shared__ float Sh[64][65];
    __shared__ float Vs[64][68];
    float acc[4][4] = {};
    const float* Kp = Kt + (row0 + lm) * EMB_D + lk;
    const float* Qp = Qt + (row0 + lm) * EMB_D + lk;
    for (int k0 = 0; k0 < EMB_D; k0 += 16) {
        float4 kv = *(const float4*)(Kp + k0);
        float4 qv = *(const float4*)(Qp + k0);
        __syncthreads();
        Ks[lk+0][lm]=kv.x; Ks[lk+1][lm]=kv.y; Ks[lk+2][lm]=kv.z; Ks[lk+3][lm]=kv.w;
        Qs[lk+0][lm]=qv.x; Qs[lk+1][lm]=qv.y; Qs[lk+2][lm]=qv.z; Qs[lk+3][lm]=qv.w;
        __syncthreads();
        #pragma unroll
        for (int kk = 0; kk < 16; ++kk) {
            float4 a = *(const float4*)(&Ks[kk][ty<<2]);
            float4 q = *(const float4*)(&Qs[kk][tx<<2]);
            float ar[4] = {a.x,a.y,a.z,a.w};
            float qr[4] = {q.x,q.y,q.z,q.w};
            #pragma unroll
            for (int i=0;i<4;i++)
                #pragma unroll
                for (int j=0;j<4;j++)
                    acc[i][j] += ar[i]*qr[j];
        }
    }
    #pragma unroll
    for (int i=0;i<4;i++) {
        const int r = (ty<<2) + i;
        #pragma unroll
        for (int j=0;j<4;j++) {
            const int c = (tx<<2) + j;
            Sh[r][c] = (c <= r) ? acc[i][j] : 0.0f;
        }
    }
    for (int e0 = 0; e0 < EMB_D; e0 += 64) {
        __syncthreads();
        #pragma unroll
        for (int it=0; it<4; ++it) {
            const int c = (it<<4) + (tid>>4);
            const int e = (tid&15)<<2;
            float4 v = *(const float4*)(Vt + (row0 + c)*EMB_D + e0 + e);
            *(float4*)(&Vs[c][e]) = v;
        }
        __syncthreads();
        float a2[4][4] = {};
        const int cend = (ty<<2) + 4;
        for (int c = 0; c < cend; ++c) {
            float4 v = *(const float4*)(&Vs[c][tx<<2]);
            const float s0 = Sh[(ty<<2)+0][c];
            const float s1 = Sh[(ty<<2)+1][c];
            const float s2 = Sh[(ty<<2)+2][c];
            const float s3 = Sh[(ty<<2)+3][c];
            a2[0][0]+=s0*v.x; a2[0][1]+=s0*v.y; a2[0][2]+=s0*v.z; a2[0][3]+=s0*v.w;
            a2[1][0]+=s1*v.x; a2[1][1]+=s1*v.y; a2[1][2]+=s1*v.z; a2[1][3]+=s1*v.w;
            a2[2][0]+=s2*v.x; a2[2][1]+=s2*v.y; a2[2][2]+=s2*v.z; a2[2][3]+=s2*v.w;
            a2[3][0]+=s3*v.x; a2[3][1]+=s3*v.y; a2[3][2]+=s3*v.z; a2[3][3]+=s3*v.w;
        }
        #pragma unroll
        for (int i=0;i<4;i++) {
            ushort4 o = { f2b(a2[i][0]), f2b(a2[i][1]), f2b(a2[i][2]), f2b(a2[i][3]) };
            *(ushort4*)(comb + (row0 + (ty<<2) + i) * (2*EMB_D) + e0 + (tx<<2)) = o;
        }
    }
}

// ---------------------------------------------------------------------------
// h2 (fp32): per (row-tile R, batch): S2[r][m] = K_(64R+r) . Q_(64m), m<=R,
// h2 = S2 @ Vsel (Vsel[m] = V_(64m)).  Writes comb[:, 512:1024] as bf16.
// ---------------------------------------------------------------------------
__device__ __forceinline__ void h2_body(
    const float* __restrict__ Kt, const float* __restrict__ Qt,
    const float* __restrict__ Vt, u16* __restrict__ comb)
{
    const int R = blockIdx.x;
    const int b = blockIdx.y;
    const size_t row0 = (size_t)b * TDIM + (size_t)R * 64;
    const size_t brow = (size_t)b * TDIM;
    const int tid = threadIdx.x;
    __shared__ float Ks2[16][64];
    __shared__ float Qs2[16][32];
    __shared__ float Sh2[64][33];
    __shared__ float Vs2[32][68];
    const int sty = tid >> 3;
    const int stx = tid & 7;
    const int lm = tid >> 2, lk = (tid & 3) << 2;
    float acc[2][4] = {};
    const float* Kp = Kt + (row0 + lm)*EMB_D + lk;
    for (int k0 = 0; k0 < EMB_D; k0 += 16) {
        float4 kv = *(const float4*)(Kp + k0);
        float4 qv = {0,0,0,0};
        if (tid < 128)
            qv = *(const float4*)(Qt + (brow + (size_t)lm*64)*EMB_D + k0 + lk);
        __syncthreads();
        Ks2[lk+0][lm]=kv.x; Ks2[lk+1][lm]=kv.y; Ks2[lk+2][lm]=kv.z; Ks2[lk+3][lm]=kv.w;
        if (tid < 128) {
            Qs2[lk+0][lm]=qv.x; Qs2[lk+1][lm]=qv.y; Qs2[lk+2][lm]=qv.z; Qs2[lk+3][lm]=qv.w;
        }
        __syncthreads();
        #pragma unroll
        for (int kk = 0; kk < 16; ++kk) {
            const float a0 = Ks2[kk][(sty<<1)+0];
            const float a1 = Ks2[kk][(sty<<1)+1];
            float4 q = *(const float4*)(&Qs2[kk][stx<<2]);
            acc[0][0]+=a0*q.x; acc[0][1]+=a0*q.y; acc[0][2]+=a0*q.z; acc[0][3]+=a0*q.w;
            acc[1][0]+=a1*q.x; acc[1][1]+=a1*q.y; acc[1][2]+=a1*q.z; acc[1][3]+=a1*q.w;
        }
    }
    #pragma unroll
    for (int i=0;i<2;i++)
        #pragma unroll
        for (int j=0;j<4;j++) {
            const int m = (stx<<2)+j;
            Sh2[(sty<<1)+i][m] = (m <= R) ? acc[i][j] : 0.0f;
        }
    const int tx = tid & 15, ty = tid >> 4;
    const int mend = R + 1;
    for (int e0 = 0; e0 < EMB_D; e0 += 64) {
        __syncthreads();
        #pragma unroll
        for (int it=0; it<2; ++it) {
            const int m = (it<<4) + (tid>>4);
            const int e = (tid&15)<<2;
            float4 v = *(const float4*)(Vt + (brow + (size_t)m*64)*EMB_D + e0 + e);
            *(float4*)(&Vs2[m][e]) = v;
        }
        __syncthreads();
        float a2[4][4] = {};
        for (int m = 0; m < mend; ++m) {
            float4 v = *(const float4*)(&Vs2[m][tx<<2]);
            const float s0 = Sh2[(ty<<2)+0][m];
            const float s1 = Sh2[(ty<<2)+1][m];
            const float s2 = Sh2[(ty<<2)+2][m];
            const float s3 = Sh2[(ty<<2)+3][m];
            a2[0][0]+=s0*v.x; a2[0][1]+=s0*v.y; a2[0][2]+=s0*v.z; a2[0][3]+=s0*v.w;
            a2[1][0]+=s1*v.x; a2[1][1]+=s1*v.y; a2[1][2]+=s1*v.z; a2[1][3]+=s1*v.w;
            a2[2][0]+=s2*v.x; a2[2][1]+=s2*v.y; a2[2][2]+=s2*v.z; a2[2][3]+=s2*v.w;
            a2[3][0]+=s3*v.x; a2[3][1]+=s3*v.y; a2[3][2]+=s3*v.z; a2[3][3]+=s3*v.w;
        }
        #pragma unroll
        for (int i=0;i<4;i++) {
            ushort4 o = { f2b(a2[i][0]), f2b(a2[i][1]), f2b(a2[i][2]), f2b(a2[i][3]) };
            *(ushort4*)(comb + (row0 + (ty<<2) + i) * (2*EMB_D) + 512 + e0 + (tx<<2)) = o;
        }
    }
}

__global__ __launch_bounds__(256) void heads_k(
    const float* __restrict__ Kt, const float* __restrict__ Qt,
    const float* __restrict__ Vt, u16* __restrict__ comb)
{
    if (blockIdx.z == 0) h1_body(Kt, Qt, Vt, comb);
    else                 h2_body(Kt, Qt, Vt, comb);
}

extern "C" void kernel_launch(void* const* d_in, const int* in_sizes, int n_in,
                              void* d_out, int out_size, void* d_ws, size_t ws_size,
                              hipStream_t stream)
{
    const float* x  = (const float*)d_in[0];
    const float* Wk = (const float*)d_in[1];
    const float* bk = (const float*)d_in[2];
    const float* Wq = (const float*)d_in[3];
    const float* bq = (const float*)d_in[4];
    const float* Wv = (const float*)d_in[5];
    const float* bv = (const float*)d_in[6];
    const float* Wu = (const float*)d_in[7];
    const float* bu = (const float*)d_in[8];
    float* out = (float*)d_out;

    char* w = (char*)d_ws;
    float* Kt    = (float*)(w + (size_t)0);
    float* Qt    = (float*)(w + ((size_t)16 << 20));
    float* Vt    = (float*)(w + ((size_t)32 << 20));
    u16*   combb = (u16*)  (w + ((size_t)48 << 20));
    u16*   xb    = (u16*)  (w + ((size_t)64 << 20));
    u16*   wkb   = (u16*)  (w + ((size_t)72 << 20));
    u16*   wqb   = (u16*)  (w + ((size_t)73 << 20));
    u16*   wvb   = (u16*)  (w + ((size_t)74 << 20));
    u16*   wub   = (u16*)  (w + ((size_t)75 << 20));

    dim3 blk(256);
    hipLaunchKernelGGL(cast_k, dim3(4096, 5), blk, 0, stream,
                       x, Wk, Wq, Wv, Wu, xb, wkb, wqb, wvb, wub);
    hipLaunchKernelGGL(qkv_gemm_k, dim3(64, 4, 3), blk, 0, stream,
                       xb, wkb, wqb, wvb, bk, bq, bv, Kt, Qt, Vt);
    hipLaunchKernelGGL(heads_k, dim3(NBLK, BB, 2), blk, 0, stream,
                       Kt, Qt, Vt, combb);
    hipLaunchKernelGGL(out_gemm_k, dim3(64, 4), blk, 0, stream,
                       combb, wub, bu, out);
}

// Round 3
// 165.192 us; speedup vs baseline: 2.9036x; 1.1398x over previous
//
#include <hip/hip_runtime.h>

// BlocksparseFixedSelfAttention: B=4, T=2048, EMB=512, KBLK=64.
// R3: all-MFMA. QKV GEMM -> bf16 K/Q/V; heads via MFMA (S in C-regs, masked,
// LDS round-trip to A-layout; V transposed to LDS for B-operand); out GEMM fp32.
// ws (MB): Ktb@0 Qtb@8 Vtb@16 | comb bf16 @24 (16MB) | xb@40 wkb@48 wqb@49 wvb@50 wub@51

typedef unsigned short u16;
typedef __attribute__((ext_vector_type(8))) short short8;
typedef __attribute__((ext_vector_type(4))) float f32x4;

constexpr int TDIM  = 2048;
constexpr int EMB_D = 512;
constexpr int BB    = 4;
constexpr int NBLK  = 32;   // T / 64

__device__ __forceinline__ u16 f2b(float f) {
    unsigned u = __float_as_uint(f);
    unsigned r = (u + 0x7FFFu + ((u >> 16) & 1u)) >> 16;
    return (u16)r;
}

// ---------------------------------------------------------------------------
// MFMA GEMM core: C[m][n] = sum_k A[m][k]*W[n][k] + bias[n].
// 128 x BN tile (BN=128 or 64), BK=32, 256 threads (4 waves).
// U16OUT: store bf16, else fp32.
// ---------------------------------------------------------------------------
template<bool U16OUT, int BN>
__device__ __forceinline__ void gemm_core(
    const u16* __restrict__ A, int lda,
    const u16* __restrict__ W, int ldw,
    const float* __restrict__ bias,
    void* __restrict__ Cp, int ldc, int K,
    int bm, int bn)
{
    __shared__ u16 As[128 * 32];
    __shared__ u16 Bs[BN * 32];
    constexpr int NT = BN / 32;            // n-tiles per wave (4 or 2)
    const int tid  = threadIdx.x;
    const int wid  = tid >> 6;
    const int lane = tid & 63;
    const int l15  = lane & 15;
    const int quad = lane >> 4;
    const int wm = (wid & 1) * 64;
    const int wn = (wid >> 1) * (BN / 2);

    f32x4 acc[4][NT] = {};

    const int srow  = tid >> 2;            // 0..63
    const int skoff = (tid & 3) * 8;
    const u16* Ag = A + (size_t)(bm + srow) * lda + skoff;
    const u16* Wg = W + (size_t)(bn + srow) * ldw + skoff;
    char* AsBase = (char*)As + wid * 1024;
    char* BsBase = (char*)Bs + wid * 1024;

    for (int k0 = 0; k0 < K; k0 += 32) {
        __syncthreads();
        __builtin_amdgcn_global_load_lds(
            (const __attribute__((address_space(1))) void*)(Ag + k0),
            (__attribute__((address_space(3))) void*)AsBase, 16, 0, 0);
        __builtin_amdgcn_global_load_lds(
            (const __attribute__((address_space(1))) void*)(Ag + (size_t)64 * lda + k0),
            (__attribute__((address_space(3))) void*)(AsBase + 4096), 16, 0, 0);
        __builtin_amdgcn_global_load_lds(
            (const __attribute__((address_space(1))) void*)(Wg + k0),
            (__attribute__((address_space(3))) void*)BsBase, 16, 0, 0);
        if (BN == 128)
            __builtin_amdgcn_global_load_lds(
                (const __attribute__((address_space(1))) void*)(Wg + (size_t)64 * ldw + k0),
                (__attribute__((address_space(3))) void*)(BsBase + 4096), 16, 0, 0);
        __syncthreads();

        short8 a[4], b[NT];
        #pragma unroll
        for (int i = 0; i < 4; ++i)
            a[i] = *(const short8*)((const short*)As + (wm + 16 * i + l15) * 32 + quad * 8);
        #pragma unroll
        for (int j = 0; j < NT; ++j)
            b[j] = *(const short8*)((const short*)Bs + (wn + 16 * j + l15) * 32 + quad * 8);
        #pragma unroll
        for (int i = 0; i < 4; ++i)
            #pragma unroll
            for (int j = 0; j < NT; ++j)
                acc[i][j] = __builtin_amdgcn_mfma_f32_16x16x32_bf16(a[i], b[j], acc[i][j], 0, 0, 0);
    }

    #pragma unroll
    for (int i = 0; i < 4; ++i) {
        #pragma unroll
        for (int j = 0; j < NT; ++j) {
            const int col = bn + wn + 16 * j + l15;
            const float bv = bias[col];
            #pragma unroll
            for (int r = 0; r < 4; ++r) {
                const int row = bm + wm + 16 * i + quad * 4 + r;
                if (U16OUT) ((u16*)Cp)[(size_t)row * ldc + col] = f2b(acc[i][j][r] + bv);
                else        ((float*)Cp)[(size_t)row * ldc + col] = acc[i][j][r] + bv;
            }
        }
    }
}

__global__ __launch_bounds__(256) void qkv_gemm_k(
    const u16* __restrict__ xb,
    const u16* __restrict__ wkb, const u16* __restrict__ wqb, const u16* __restrict__ wvb,
    const float* __restrict__ bk, const float* __restrict__ bq, const float* __restrict__ bv,
    u16* __restrict__ Ktb, u16* __restrict__ Qtb, u16* __restrict__ Vtb)
{
    const u16* W; const float* bias; u16* C;
    if (blockIdx.z == 0)      { W = wkb; bias = bk; C = Ktb; }
    else if (blockIdx.z == 1) { W = wqb; bias = bq; C = Qtb; }
    else                      { W = wvb; bias = bv; C = Vtb; }
    gemm_core<true, 64>(xb, EMB_D, W, EMB_D, bias, C, EMB_D, EMB_D,
                        blockIdx.x * 128, blockIdx.y * 64);
}

__global__ __launch_bounds__(256) void out_gemm_k(
    const u16* __restrict__ combb, const u16* __restrict__ wub,
    const float* __restrict__ bu, float* __restrict__ out)
{
    gemm_core<false, 64>(combb, 2 * EMB_D, wub, 2 * EMB_D, bu, out, EMB_D, 2 * EMB_D,
                         blockIdx.x * 128, blockIdx.y * 64);
}

// ---------------------------------------------------------------------------
// cast: x + 4 weights -> bf16.
// ---------------------------------------------------------------------------
__global__ __launch_bounds__(256) void cast_k(
    const float* __restrict__ x, const float* __restrict__ wk, const float* __restrict__ wq,
    const float* __restrict__ wv, const float* __restrict__ wu,
    u16* __restrict__ xb, u16* __restrict__ wkb, u16* __restrict__ wqb,
    u16* __restrict__ wvb, u16* __restrict__ wub)
{
    const int s = blockIdx.y;
    int n; const float* src; u16* dst;
    switch (s) {
        case 0: n = 4194304; src = x;  dst = xb;  break;
        case 1: n = 262144;  src = wk; dst = wkb; break;
        case 2: n = 262144;  src = wq; dst = wqb; break;
        case 3: n = 262144;  src = wv; dst = wvb; break;
        default: n = 524288; src = wu; dst = wub; break;
    }
    const int idx = (blockIdx.x * 256 + threadIdx.x) * 4;
    if (idx >= n) return;
    float4 v = *(const float4*)(src + idx);
    ushort4 o = { f2b(v.x), f2b(v.y), f2b(v.z), f2b(v.w) };
    *(ushort4*)(dst + idx) = o;
}

// ---------------------------------------------------------------------------
// heads (all-MFMA): grid (32 blk, 4 b, 8 z). z<4: h1 e-chunk z*128; z>=4: h2.
// h1: S = K_blk.Q_blk^T (64x64,K=512) masked c<=r; out = S.V_blk[:,e0:e0+128].
// h2: S2 = K_blk.Qsel^T (64x32,K=512) masked m<=blk; out = S2.Vsel[:,e0:+128].
// S via direct-global MFMA frags; V^T staged in LDS for the B operand.
// LDS strides 72/40 u16 (144/80B: 16B-aligned, 2-way banks = free).
// ---------------------------------------------------------------------------
__global__ __launch_bounds__(256) void heads_k(
    const u16* __restrict__ Ktb, const u16* __restrict__ Qtb,
    const u16* __restrict__ Vtb, u16* __restrict__ comb)
{
    __shared__ u16 sm1[64 * 72];    // S (h1: stride 72) / S2 (h2: stride 40)
    __shared__ u16 sm2[128 * 72];   // V^T chunk (h1: [e][c] stride 72) / VTsel (h2: stride 40)
    const int blk = blockIdx.x, b = blockIdx.y, z = blockIdx.z;
    const int tid = threadIdx.x;
    const int wid = tid >> 6, lane = tid & 63;
    const int l15 = lane & 15, quad = lane >> 4;
    const size_t row0 = (size_t)b * TDIM + (size_t)blk * 64;
    const int srow_base = 16 * wid + quad * 4;

    if (z < 4) {
        const int e0 = z * 128;
        // ---- Phase A: S ----
        f32x4 s[4] = {};
        const u16* Kp = Ktb + (row0 + 16 * wid + l15) * EMB_D + quad * 8;
        const u16* Qp = Qtb + (row0 + l15) * EMB_D + quad * 8;
        for (int ks = 0; ks < 16; ++ks) {
            short8 af = *(const short8*)(Kp + 32 * ks);
            #pragma unroll
            for (int j = 0; j < 4; ++j) {
                short8 bf = *(const short8*)(Qp + (size_t)(16 * j) * EMB_D + 32 * ks);
                s[j] = __builtin_amdgcn_mfma_f32_16x16x32_bf16(af, bf, s[j], 0, 0, 0);
            }
        }
        // mask c<=r, store S to LDS bf16 (row-major, stride 72)
        #pragma unroll
        for (int j = 0; j < 4; ++j)
            #pragma unroll
            for (int r = 0; r < 4; ++r) {
                const int rr = srow_base + r;
                const int cc = 16 * j + l15;
                sm1[rr * 72 + cc] = f2b((cc <= rr) ? s[j][r] : 0.0f);
            }
        // ---- stage V^T chunk: VT[e (128)][c (64)] ----
        #pragma unroll
        for (int it = 0; it < 4; ++it) {
            const int id = tid + 256 * it;
            const int c  = id & 63;
            const int eo = (id >> 6) * 8;
            short8 v = *(const short8*)(Vtb + (row0 + c) * EMB_D + e0 + eo);
            #pragma unroll
            for (int i = 0; i < 8; ++i) sm2[(eo + i) * 72 + c] = (u16)v[i];
        }
        __syncthreads();
        // ---- Phase B: out = S @ V  (K=64, N=128) ----
        f32x4 o[8] = {};
        const u16* arow = sm1 + (16 * wid + l15) * 72;
        #pragma unroll
        for (int ks = 0; ks < 2; ++ks) {
            short8 as = *(const short8*)(arow + 32 * ks + quad * 8);
            #pragma unroll
            for (int nt = 0; nt < 8; ++nt) {
                short8 bs = *(const short8*)(sm2 + (16 * nt + l15) * 72 + 32 * ks + quad * 8);
                o[nt] = __builtin_amdgcn_mfma_f32_16x16x32_bf16(as, bs, o[nt], 0, 0, 0);
            }
        }
        #pragma unroll
        for (int nt = 0; nt < 8; ++nt)
            #pragma unroll
            for (int r = 0; r < 4; ++r)
                comb[(row0 + srow_base + r) * (2 * EMB_D) + e0 + 16 * nt + l15] = f2b(o[nt][r]);
    } else {
        const int R = blk;
        const int e0 = (z - 4) * 128;
        // ---- Phase A: S2 (64x32) ----
        f32x4 s[2] = {};
        const u16* Kp = Ktb + (row0 + 16 * wid + l15) * EMB_D + quad * 8;
        const u16* Qp = Qtb + ((size_t)b * TDIM + (size_t)64 * l15) * EMB_D + quad * 8;
        for (int ks = 0; ks < 16; ++ks) {
            short8 af = *(const short8*)(Kp + 32 * ks);
            #pragma unroll
            for (int j = 0; j < 2; ++j) {
                short8 bf = *(const short8*)(Qp + (size_t)(64 * 16 * j) * EMB_D + 32 * ks);
                s[j] = __builtin_amdgcn_mfma_f32_16x16x32_bf16(af, bf, s[j], 0, 0, 0);
            }
        }
        #pragma unroll
        for (int j = 0; j < 2; ++j)
            #pragma unroll
            for (int r = 0; r < 4; ++r) {
                const int m  = 16 * j + l15;
                const int rr = srow_base + r;
                sm1[rr * 40 + m] = f2b((m <= R) ? s[j][r] : 0.0f);
            }
        // ---- stage VTsel[e (128)][m (32)] = V[64m][e0+e] ----
        #pragma unroll
        for (int it = 0; it < 2; ++it) {
            const int id = tid + 256 * it;
            const int m  = id & 31;
            const int eo = (id >> 5) * 8;
            short8 v = *(const short8*)(Vtb + ((size_t)b * TDIM + 64 * m) * EMB_D + e0 + eo);
            #pragma unroll
            for (int i = 0; i < 8; ++i) sm2[(eo + i) * 40 + m] = (u16)v[i];
        }
        __syncthreads();
        // ---- Phase B: out = S2 @ Vsel  (K=32, N=128) ----
        f32x4 o[8] = {};
        short8 as = *(const short8*)(sm1 + (16 * wid + l15) * 40 + quad * 8);
        #pragma unroll
        for (int nt = 0; nt < 8; ++nt) {
            short8 bs = *(const short8*)(sm2 + (16 * nt + l15) * 40 + quad * 8);
            o[nt] = __builtin_amdgcn_mfma_f32_16x16x32_bf16(as, bs, o[nt], 0, 0, 0);
        }
        #pragma unroll
        for (int nt = 0; nt < 8; ++nt)
            #pragma unroll
            for (int r = 0; r < 4; ++r)
                comb[(row0 + srow_base + r) * (2 * EMB_D) + EMB_D + e0 + 16 * nt + l15] = f2b(o[nt][r]);
    }
}

extern "C" void kernel_launch(void* const* d_in, const int* in_sizes, int n_in,
                              void* d_out, int out_size, void* d_ws, size_t ws_size,
                              hipStream_t stream)
{
    const float* x  = (const float*)d_in[0];
    const float* Wk = (const float*)d_in[1];
    const float* bk = (const float*)d_in[2];
    const float* Wq = (const float*)d_in[3];
    const float* bq = (const float*)d_in[4];
    const float* Wv = (const float*)d_in[5];
    const float* bv = (const float*)d_in[6];
    const float* Wu = (const float*)d_in[7];
    const float* bu = (const float*)d_in[8];
    float* out = (float*)d_out;

    char* w = (char*)d_ws;
    u16* Ktb   = (u16*)(w + ((size_t)0  << 20));
    u16* Qtb   = (u16*)(w + ((size_t)8  << 20));
    u16* Vtb   = (u16*)(w + ((size_t)16 << 20));
    u16* combb = (u16*)(w + ((size_t)24 << 20));
    u16* xb    = (u16*)(w + ((size_t)40 << 20));
    u16* wkb   = (u16*)(w + ((size_t)48 << 20));
    u16* wqb   = (u16*)(w + ((size_t)49 << 20));
    u16* wvb   = (u16*)(w + ((size_t)50 << 20));
    u16* wub   = (u16*)(w + ((size_t)51 << 20));

    dim3 blk(256);
    hipLaunchKernelGGL(cast_k, dim3(4096, 5), blk, 0, stream,
                       x, Wk, Wq, Wv, Wu, xb, wkb, wqb, wvb, wub);
    hipLaunchKernelGGL(qkv_gemm_k, dim3(64, 8, 3), blk, 0, stream,
                       xb, wkb, wqb, wvb, bk, bq, bv, Ktb, Qtb, Vtb);
    hipLaunchKernelGGL(heads_k, dim3(NBLK, BB, 8), blk, 0, stream,
                       Ktb, Qtb, Vtb, combb);
    hipLaunchKernelGGL(out_gemm_k, dim3(64, 8), blk, 0, stream,
                       combb, wub, bu, out);
}